// Round 1
// 507.045 us; speedup vs baseline: 1.0624x; 1.0624x over previous
//
#include <hip/hip_runtime.h>

typedef unsigned short u16;
typedef unsigned int u32;
typedef __bf16 bf16x8 __attribute__((ext_vector_type(8)));
typedef __bf16 bf16x4 __attribute__((ext_vector_type(4)));
typedef float f32x4 __attribute__((ext_vector_type(4)));

#define MFMA16(a, b, c) __builtin_amdgcn_mfma_f32_16x16x32_bf16(a, b, c, 0, 0, 0)

__device__ __forceinline__ u16 f2bf(float f) {
  u32 u = __float_as_uint(f);
  u += 0x7FFFu + ((u >> 16) & 1u);
  return (u16)(u >> 16);
}
__device__ __forceinline__ float bf2f(u16 h) {
  return __uint_as_float(((u32)h) << 16);
}

__device__ __forceinline__ void gload_lds16(const u16* g, u16* l) {
  __builtin_amdgcn_global_load_lds((__attribute__((address_space(1))) void*)g,
                                   (__attribute__((address_space(3))) void*)l,
                                   16, 0, 0);
}

// ---------------------------------------------------------------------------
// fp32 -> bf16 elementwise convert (x). 4 elems/thread.
// ---------------------------------------------------------------------------
__global__ __launch_bounds__(256) void cvt_x(const float* __restrict__ in,
                                             u16* __restrict__ out) {
  int i = (blockIdx.x * 256 + threadIdx.x) * 4;
  float4 v = *(const float4*)&in[i];
  ushort4 o;
  o.x = f2bf(v.x);
  o.y = f2bf(v.y);
  o.z = f2bf(v.z);
  o.w = f2bf(v.w);
  *(ushort4*)&out[i] = o;
}

// ---------------------------------------------------------------------------
// Transpose + convert: in[R][C] fp32 (row stride ldin) -> out[C][R] bf16
// ---------------------------------------------------------------------------
__global__ __launch_bounds__(256) void tbf_f2b(const float* __restrict__ in,
                                               u16* __restrict__ out,
                                               int ldin, int ldout) {
  __shared__ float tile[64][65];
  const int t = threadIdx.x;
  const int c4 = t & 15;
  const int rb = t >> 4;
  const int r0 = blockIdx.y * 64;
  const int c0 = blockIdx.x * 64;
#pragma unroll
  for (int p = 0; p < 4; p++) {
    int r = p * 16 + rb;
    float4 v = *(const float4*)&in[(size_t)(r0 + r) * ldin + c0 + c4 * 4];
    tile[r][c4 * 4 + 0] = v.x;
    tile[r][c4 * 4 + 1] = v.y;
    tile[r][c4 * 4 + 2] = v.z;
    tile[r][c4 * 4 + 3] = v.w;
  }
  __syncthreads();
#pragma unroll
  for (int p = 0; p < 4; p++) {
    int oc = p * 16 + rb;
    ushort4 v;
    v.x = f2bf(tile[c4 * 4 + 0][oc]);
    v.y = f2bf(tile[c4 * 4 + 1][oc]);
    v.z = f2bf(tile[c4 * 4 + 2][oc]);
    v.w = f2bf(tile[c4 * 4 + 3][oc]);
    *(ushort4*)&out[(size_t)(c0 + oc) * ldout + r0 + c4 * 4] = v;
  }
}

// ---------------------------------------------------------------------------
// bf16 transpose: in[R][C] -> out[C][R]
// ---------------------------------------------------------------------------
__global__ __launch_bounds__(256) void tbf_b(const u16* __restrict__ in,
                                             u16* __restrict__ out,
                                             int ldin, int ldout) {
  __shared__ u16 tile[64][68];
  const int t = threadIdx.x;
  const int c4 = t & 15;
  const int rb = t >> 4;
  const int r0 = blockIdx.y * 64;
  const int c0 = blockIdx.x * 64;
#pragma unroll
  for (int p = 0; p < 4; p++) {
    int r = p * 16 + rb;
    ushort4 v = *(const ushort4*)&in[(size_t)(r0 + r) * ldin + c0 + c4 * 4];
    *(ushort4*)&tile[r][c4 * 4] = v;
  }
  __syncthreads();
#pragma unroll
  for (int p = 0; p < 4; p++) {
    int oc = p * 16 + rb;
    ushort4 v;
    v.x = tile[c4 * 4 + 0][oc];
    v.y = tile[c4 * 4 + 1][oc];
    v.z = tile[c4 * 4 + 2][oc];
    v.w = tile[c4 * 4 + 3][oc];
    *(ushort4*)&out[(size_t)(c0 + oc) * ldout + r0 + c4 * 4] = v;
  }
}

// ---------------------------------------------------------------------------
// 256-wide deep-pipelined bf16 GEMM: C[M][N] = A[M][K] @ B^T, B stored [N][K].
// BM=256, BK=64, BN template (192 or 128). 8 waves (512 thr), wave grid 2x4,
// per-wave output 128 x (BN/4). Double-buffered LDS, 1-K-tile-ahead staging
// via global_load_lds with counted vmcnt (never 0 mid-loop) + raw s_barrier.
// LDS tiles [rows][64] bf16 with 16B-chunk XOR swizzle h ^= (r&7):
// conflict-free ds_read_b128 (each 8-lane group covers all 8 chunk slots).
// Swizzle applied by pre-swizzling the GLOBAL source addr (gload_lds writes
// lane-linear) and on the LDS read addr -- both-sides-or-neither (rule #21).
// XCD-chunked remap: id&7 -> M-panel so each XCD's 32 CUs share one A-panel.
// ---------------------------------------------------------------------------
template <int BN, int F32OUT>
__global__ __launch_bounds__(512, 2) void gemm256(const u16* __restrict__ A,
                                                  const u16* __restrict__ B,
                                                  void* __restrict__ Cv,
                                                  int K, int ldc) {
  constexpr int NJ = BN / 64;  // B frags per wave per k-step; also B stage instrs
  __shared__ __attribute__((aligned(16))) u16 As[2][256 * 64];
  __shared__ __attribute__((aligned(16))) u16 Bs[2][BN * 64];
  const int tid = threadIdx.x;
  const int wave = tid >> 6;
  const int lane = tid & 63;
  const int l16 = lane & 15;
  const int quad = lane >> 4;
  const int wm = wave >> 2;
  const int wn = wave & 3;
  const int id = blockIdx.y * gridDim.x + blockIdx.x;  // 256 blocks
  const int bm = (id & 7) * 256;                       // XCD k -> row panel k
  const int bn0 = (id >> 3) * BN;

  // staging source pointers (pre-swizzled: chunk c holds logical chunk c^(r&7))
  const u16* srcA[4];
  const u16* srcB[NJ];
#pragma unroll
  for (int m = 0; m < 4; m++) {
    int c = (wave * 4 + m) * 64 + lane;
    int r = c >> 3;
    int hl = (c & 7) ^ (r & 7);
    srcA[m] = A + (size_t)(bm + r) * K + hl * 8;
  }
#pragma unroll
  for (int m = 0; m < NJ; m++) {
    int c = (wave * NJ + m) * 64 + lane;
    int r = c >> 3;
    int hl = (c & 7) ^ (r & 7);
    srcB[m] = B + (size_t)(bn0 + r) * K + hl * 8;
  }

  f32x4 acc[8][NJ];
#pragma unroll
  for (int i = 0; i < 8; i++)
#pragma unroll
    for (int j = 0; j < NJ; j++) acc[i][j] = (f32x4){0.f, 0.f, 0.f, 0.f};

  auto stage = [&](int nb) {
#pragma unroll
    for (int m = 0; m < 4; m++) {
      gload_lds16(srcA[m], &As[nb][(size_t)((wave * 4 + m) * 64 + lane) * 8]);
      srcA[m] += 64;
    }
#pragma unroll
    for (int m = 0; m < NJ; m++) {
      gload_lds16(srcB[m], &Bs[nb][(size_t)((wave * NJ + m) * 64 + lane) * 8]);
      srcB[m] += 64;
    }
  };

  stage(0);  // prologue: tile 0 in flight
  const int NT = K >> 6;
  int cur = 0;
  for (int t = 0; t < NT; ++t) {
    if (t + 1 < NT) {
      stage(cur ^ 1);  // issue tile t+1 before waiting on tile t
      // wait until only tile t+1's (4+NJ) loads remain -> tile t landed
      if constexpr (NJ == 3)
        asm volatile("s_waitcnt vmcnt(7)" ::: "memory");
      else
        asm volatile("s_waitcnt vmcnt(6)" ::: "memory");
    } else {
      asm volatile("s_waitcnt vmcnt(0)" ::: "memory");
    }
    __builtin_amdgcn_s_barrier();  // raw: no vmcnt(0) drain of in-flight tile
    __builtin_amdgcn_sched_barrier(0);
    const u16* as = &As[cur][0];
    const u16* bs = &Bs[cur][0];
#pragma unroll
    for (int ks = 0; ks < 2; ks++) {
      bf16x8 bfr[NJ];
#pragma unroll
      for (int j = 0; j < NJ; j++) {
        int r = wn * (BN / 4) + j * 16 + l16;
        int h = (ks * 4 + quad) ^ (r & 7);
        bfr[j] = *(const bf16x8*)&bs[r * 64 + h * 8];
      }
#pragma unroll
      for (int ih = 0; ih < 2; ih++) {
        bf16x8 afr[4];
#pragma unroll
        for (int i = 0; i < 4; i++) {
          int r = wm * 128 + ih * 64 + i * 16 + l16;
          int h = (ks * 4 + quad) ^ (r & 7);
          afr[i] = *(const bf16x8*)&as[r * 64 + h * 8];
        }
        __builtin_amdgcn_s_setprio(1);
#pragma unroll
        for (int i = 0; i < 4; i++)
#pragma unroll
          for (int j = 0; j < NJ; j++)
            acc[ih * 4 + i][j] = MFMA16(afr[i], bfr[j], acc[ih * 4 + i][j]);
        __builtin_amdgcn_s_setprio(0);
      }
    }
    __builtin_amdgcn_sched_barrier(0);
    __builtin_amdgcn_s_barrier();  // all waves done reading buf[cur] before it
    cur ^= 1;                      // is overwritten by next iteration's stage
  }

  const int wcol = bn0 + wn * (BN / 4);
  if constexpr (F32OUT) {
    float* C = (float*)Cv;
#pragma unroll
    for (int ih = 0; ih < 2; ih++)
#pragma unroll
      for (int i = 0; i < 4; i++)
#pragma unroll
        for (int j = 0; j < NJ; j++)
#pragma unroll
          for (int r = 0; r < 4; r++) {
            int row = bm + wm * 128 + ih * 64 + i * 16 + quad * 4 + r;
            int col = wcol + j * 16 + l16;
            C[(size_t)row * ldc + col] = acc[ih * 4 + i][j][r];
          }
  } else {
    u16* C = (u16*)Cv;
#pragma unroll
    for (int ih = 0; ih < 2; ih++)
#pragma unroll
      for (int i = 0; i < 4; i++)
#pragma unroll
        for (int j = 0; j < NJ; j++)
#pragma unroll
          for (int r = 0; r < 4; r++) {
            int row = bm + wm * 128 + ih * 64 + i * 16 + quad * 4 + r;
            int col = wcol + j * 16 + l16;
            C[(size_t)row * ldc + col] = f2bf(acc[ih * 4 + i][j][r]);
          }
  }
}

// ---------------------------------------------------------------------------
// In-place RoPE on Q (cols 0..4095) and K (cols 4096..5119) of qkv[2048][6144].
// ---------------------------------------------------------------------------
__global__ __launch_bounds__(256) void rope_k(u16* __restrict__ qkv,
                                              const float* __restrict__ fc,
                                              const float* __restrict__ fs) {
  int idx = blockIdx.x * 256 + threadIdx.x;
  int j = idx & 63;
  int rem = idx >> 6;
  int head = rem % 40;
  int s = rem / 40;
  float c = fc[s * 64 + j];
  float sn = fs[s * 64 + j];
  int col = (head < 32) ? (head * 128 + 2 * j) : (4096 + (head - 32) * 128 + 2 * j);
  u32* p = (u32*)&qkv[(size_t)s * 6144 + col];
  u32 v = *p;
  float e = bf2f((u16)(v & 0xFFFFu));
  float o = bf2f((u16)(v >> 16));
  float re = e * c - o * sn;
  float ro = e * sn + o * c;
  *p = (u32)f2bf(re) | ((u32)f2bf(ro) << 16);
}

// ---------------------------------------------------------------------------
// Sliding-window causal GQA attention, LDS-staged K/V, unshifted softmax.
// grid = (32 heads, 16 q-blocks of 128), block = 256 (4 waves, 32 q/wave).
// ---------------------------------------------------------------------------
__global__ __launch_bounds__(256) void attn_k(const u16* __restrict__ qkv,
                                              const u16* __restrict__ vt,
                                              u16* __restrict__ outb) {
  __shared__ __attribute__((aligned(16))) u16 Kb[2][32 * 128];
  __shared__ __attribute__((aligned(16))) u16 Vb[2][128 * 32];
  __shared__ __attribute__((aligned(16))) u16 plds[4][32 * 36];
  const int h = blockIdx.x;
  const int q0 = blockIdx.y * 128;
  const int t = threadIdx.x;
  const int wave = t >> 6;
  const int lane = t & 63;
  const int l16 = lane & 15;
  const int quad = lane >> 4;
  const int hkv = h >> 2;
  const int qw = q0 + wave * 32;
  u16* myp = &plds[wave][0];

  // Q fragments: 2 sets of 16 rows
  bf16x8 qa[2][4];
#pragma unroll
  for (int i = 0; i < 2; i++)
#pragma unroll
    for (int kc = 0; kc < 4; kc++)
      qa[i][kc] = *(const bf16x8*)&qkv[(size_t)(qw + i * 16 + l16) * 6144 +
                                       h * 128 + kc * 32 + quad * 8];

  f32x4 o[2][8];
#pragma unroll
  for (int i = 0; i < 2; i++)
#pragma unroll
    for (int d = 0; d < 8; d++) o[i][d] = (f32x4){0.f, 0.f, 0.f, 0.f};
  float lloc[2][4] = {{0.f, 0.f, 0.f, 0.f}, {0.f, 0.f, 0.f, 0.f}};

  const int kb_start = (q0 - 1023 > 0 ? q0 - 1023 : 0) & ~31;
  const int kb_last = q0 + 96;  // (q0+127) & ~31
  const float sc = 0.08838834764831845f;  // 1/sqrt(128)

  // staging indices (swizzled): K chunk c -> row c>>4, stored col (c&15),
  // data col (c&15)^(row&15). V chunk c -> row c>>2, data col (c&3)^(row&3).
  const int kr0 = t >> 4, kc0s = t & 15;
  const int kr1 = (256 + t) >> 4, kc1s = t & 15;
  const int vr0 = t >> 2, vc0s = t & 3;
  const int vr1 = (256 + t) >> 2, vc1s = t & 3;
  const u16* kg = qkv + 4096 + hkv * 128;
  const u16* vg = vt + (size_t)hkv * 128 * 2048;

#define STAGE(kb_, nb_)                                                        \
  do {                                                                         \
    int kb__ = (kb_);                                                          \
    gload_lds16(&kg[(size_t)(kb__ + kr0) * 6144 + (kc0s ^ (kr0 & 15)) * 8],    \
                &Kb[nb_][t * 8]);                                              \
    gload_lds16(&kg[(size_t)(kb__ + kr1) * 6144 + (kc1s ^ (kr1 & 15)) * 8],    \
                &Kb[nb_][2048 + t * 8]);                                       \
    gload_lds16(&vg[(size_t)vr0 * 2048 + kb__ + (vc0s ^ (vr0 & 3)) * 8],       \
                &Vb[nb_][t * 8]);                                              \
    gload_lds16(&vg[(size_t)vr1 * 2048 + kb__ + (vc1s ^ (vr1 & 3)) * 8],       \
                &Vb[nb_][2048 + t * 8]);                                       \
  } while (0)

  STAGE(kb_start, 0);
  int cur = 0;

  for (int kb = kb_start; kb <= kb_last; kb += 32) {
    __syncthreads();  // drains vmcnt: buf[cur] staged; all waves done with prev
    if (kb + 32 <= kb_last) STAGE(kb + 32, cur ^ 1);
    const u16* kcur = &Kb[cur][0];
    const u16* vcur = &Vb[cur][0];

    // ---- QK^T: 32q x 32k ----
    f32x4 s0[2] = {(f32x4){0.f, 0.f, 0.f, 0.f}, (f32x4){0.f, 0.f, 0.f, 0.f}};
    f32x4 s1[2] = {(f32x4){0.f, 0.f, 0.f, 0.f}, (f32x4){0.f, 0.f, 0.f, 0.f}};
#pragma unroll
    for (int kc = 0; kc < 4; kc++) {
      int ch = ((kc * 4 + quad) ^ l16) * 8;
      bf16x8 b0 = *(const bf16x8*)&kcur[l16 * 128 + ch];
      bf16x8 b1 = *(const bf16x8*)&kcur[(l16 + 16) * 128 + ch];
      s0[0] = MFMA16(qa[0][kc], b0, s0[0]);
      s1[0] = MFMA16(qa[0][kc], b1, s1[0]);
      s0[1] = MFMA16(qa[1][kc], b0, s0[1]);
      s1[1] = MFMA16(qa[1][kc], b1, s1[1]);
    }

    // ---- unshifted softmax numerator + pack ----
    float p0[2][4], p1[2][4];
    bool fast = (kb + 31 <= qw) && (qw + 31 - kb <= 1023);
    if (fast) {
#pragma unroll
      for (int i = 0; i < 2; i++)
#pragma unroll
        for (int r = 0; r < 4; r++) {
          p0[i][r] = __expf(s0[i][r] * sc);
          p1[i][r] = __expf(s1[i][r] * sc);
        }
    } else {
#pragma unroll
      for (int i = 0; i < 2; i++)
#pragma unroll
        for (int r = 0; r < 4; r++) {
          int row = qw + i * 16 + quad * 4 + r;
          int col0 = kb + l16;
          int col1 = col0 + 16;
          bool v0 = (col0 <= row) && (row - col0 < 1024);
          bool v1 = (col1 <= row) && (row - col1 < 1024);
          p0[i][r] = v0 ? __expf(s0[i][r] * sc) : 0.f;
          p1[i][r] = v1 ? __expf(s1[i][r] * sc) : 0.f;
        }
    }
#pragma unroll
    for (int i = 0; i < 2; i++)
#pragma unroll
      for (int r = 0; r < 4; r++) {
        lloc[i][r] += p0[i][r] + p1[i][r];
        myp[(i * 16 + quad * 4 + r) * 36 + l16] = f2bf(p0[i][r]);
        myp[(i * 16 + quad * 4 + r) * 36 + l16 + 16] = f2bf(p1[i][r]);
      }
    asm volatile("s_waitcnt lgkmcnt(0)" ::: "memory");
    bf16x8 pa[2];
#pragma unroll
    for (int i = 0; i < 2; i++) {
      bf16x4 lo = *(const bf16x4*)&myp[(i * 16 + l16) * 36 + quad * 8];
      bf16x4 hi = *(const bf16x4*)&myp[(i * 16 + l16) * 36 + quad * 8 + 4];
#pragma unroll
      for (int j = 0; j < 4; j++) {
        pa[i][j] = lo[j];
        pa[i][j + 4] = hi[j];
      }
    }
    // ---- PV: V fragments read once, shared by both A-frag sets ----
#pragma unroll
    for (int d = 0; d < 8; d++) {
      int rv = l16 + 16 * d;
      bf16x8 vb = *(const bf16x8*)&vcur[rv * 32 + ((quad ^ (l16 & 3)) * 8)];
      o[0][d] = MFMA16(pa[0], vb, o[0][d]);
      o[1][d] = MFMA16(pa[1], vb, o[1][d]);
    }
    cur ^= 1;
  }

  // ---- final row-sum reduce + divide + store ----
#pragma unroll
  for (int i = 0; i < 2; i++) {
    float inv[4];
#pragma unroll
    for (int r = 0; r < 4; r++) {
      float l = lloc[i][r];
#pragma unroll
      for (int m = 8; m >= 1; m >>= 1) l += __shfl_xor(l, m, 64);
      inv[r] = 1.0f / l;
    }
#pragma unroll
    for (int d = 0; d < 8; d++)
#pragma unroll
      for (int r = 0; r < 4; r++) {
        int row = qw + i * 16 + quad * 4 + r;
        outb[(size_t)row * 4096 + h * 128 + d * 16 + l16] =
            f2bf(o[i][d][r] * inv[r]);
      }
  }
#undef STAGE
}

// ---------------------------------------------------------------------------
// Workspace layout (bytes):
//   0         : xb    [2048][4096] bf16 (16777216)
//   16777216  : wqkvT [6144][4096] bf16 (50331648)  (wq rows 0..4095,
//               wk rows 4096..5119, wv rows 5120..6143; contiguous)
//               -- reused for woT [4096][4096] after GEMM1
//   67108864  : qkvb  [2048][6144] bf16 (25165824)
//   92274688  : vtb   [1024][2048] bf16 ( 4194304)
//   96468992  : aout  [2048][4096] bf16 (16777216)
// ---------------------------------------------------------------------------
extern "C" void kernel_launch(void* const* d_in, const int* in_sizes, int n_in,
                              void* d_out, int out_size, void* d_ws, size_t ws_size,
                              hipStream_t stream) {
  const float* x = (const float*)d_in[0];
  const float* fc = (const float*)d_in[1];
  const float* fs = (const float*)d_in[2];
  // d_in[3] = mask (unused; recomputed analytically)
  const float* wq = (const float*)d_in[4];
  const float* wk = (const float*)d_in[5];
  const float* wv = (const float*)d_in[6];
  const float* wo = (const float*)d_in[7];
  float* outp = (float*)d_out;
  char* ws = (char*)d_ws;
  u16* xb = (u16*)(ws);
  u16* wqkvT = (u16*)(ws + 16777216);
  u16* qkvb = (u16*)(ws + 67108864);
  u16* vtb = (u16*)(ws + 92274688);
  u16* aout = (u16*)(ws + 96468992);

  cvt_x<<<8192, 256, 0, stream>>>(x, xb);
  tbf_f2b<<<dim3(64, 64), 256, 0, stream>>>(wq, wqkvT, 4096, 4096);
  tbf_f2b<<<dim3(16, 64), 256, 0, stream>>>(wk, wqkvT + (size_t)4096 * 4096,
                                            1024, 4096);
  tbf_f2b<<<dim3(16, 64), 256, 0, stream>>>(wv, wqkvT + (size_t)5120 * 4096,
                                            1024, 4096);
  gemm256<192, 0><<<dim3(32, 8), 512, 0, stream>>>(xb, wqkvT, qkvb, 4096, 6144);
  rope_k<<<20480, 256, 0, stream>>>(qkvb, fc, fs);
  tbf_b<<<dim3(16, 32), 256, 0, stream>>>(qkvb + 5120, vtb, 6144, 2048);
  tbf_f2b<<<dim3(64, 64), 256, 0, stream>>>(wo, wqkvT, 4096, 4096);
  attn_k<<<dim3(32, 16), 256, 0, stream>>>(qkvb, vtb, aout);
  gemm256<128, 1><<<dim3(32, 8), 512, 0, stream>>>(aout, wqkvT, outp, 4096,
                                                   4096);
}